// Round 6
// baseline (474.664 us; speedup 1.0000x reference)
//
#include <hip/hip_runtime.h>

#define NB 8
#define NN 2048
#define NF 256

typedef __attribute__((ext_vector_type(8))) short bf16x8;
typedef __attribute__((ext_vector_type(4))) float f32x4;

__device__ __forceinline__ unsigned short f2bf(float x) {
  union { float f; unsigned int i; } c; c.f = x;
  unsigned int r = c.i + 0x7FFFu + ((c.i >> 16) & 1u);
  return (unsigned short)(r >> 16);
}
// round-half-up bf16 (1 add + 1 shift) — hot convert paths
__device__ __forceinline__ unsigned short f2bf_fast(float x) {
  union { float f; unsigned int i; } c; c.f = x;
  return (unsigned short)((c.i + 0x8000u) >> 16);
}
__device__ __forceinline__ bf16x8 cvt8(float4 c0, float4 c1) {
  union { bf16x8 v8; unsigned short us[8]; } cu;
  cu.us[0] = f2bf_fast(c0.x); cu.us[1] = f2bf_fast(c0.y);
  cu.us[2] = f2bf_fast(c0.z); cu.us[3] = f2bf_fast(c0.w);
  cu.us[4] = f2bf_fast(c1.x); cu.us[5] = f2bf_fast(c1.y);
  cu.us[6] = f2bf_fast(c1.z); cu.us[7] = f2bf_fast(c1.w);
  return cu.v8;
}

// ---------------------------------------------------------------------------
// k_prep: WT[f][k] = bf16(W[k][f]);  u = W @ a1, v = W @ a2  (fp32)
// ---------------------------------------------------------------------------
__global__ __launch_bounds__(256) void k_prep(
    const float* __restrict__ W, const float* __restrict__ a,
    unsigned short* __restrict__ WT, float* __restrict__ u, float* __restrict__ v) {
  int t = threadIdx.x;
  if (blockIdx.x < 256) {
    int k = blockIdx.x;
    WT[t * 256 + k] = f2bf(W[k * 256 + t]);
  } else {
    float su = 0.f, sv = 0.f;
    for (int o = 0; o < 256; ++o) {
      float w = W[t * 256 + o];
      su += w * a[o];
      sv += w * a[256 + o];
    }
    u[t] = su; v[t] = sv;
  }
}

// ---------------------------------------------------------------------------
// k_wht: WhT[b][f][i] = sum_k W[k][f] * h[b][i][k]
// grid 512: b(8) x [fblk(4,64f) x iblk(16,128i)]; 4 waves (2f x 2i), wave 32f x 64i
// ---------------------------------------------------------------------------
__global__ __launch_bounds__(256) void k_wht(
    const float* __restrict__ h, const unsigned short* __restrict__ WTr,
    unsigned short* __restrict__ WhT) {
  int bx = blockIdx.x;
  int b = bx >> 6;
  int t = bx & 63;
  int fBlk = (t >> 4) * 64;
  int iBlk = (t & 15) * 128;
  int wave = threadIdx.x >> 6, lane = threadIdx.x & 63;
  int fW = fBlk + (wave >> 1) * 32;
  int iW = iBlk + (wave & 1) * 64;
  int l15 = lane & 15, q8 = (lane >> 4) * 8;
  const float* hB = h + (size_t)b * NN * NF;

  f32x4 acc[2][4];
#pragma unroll
  for (int mt = 0; mt < 2; ++mt)
#pragma unroll
    for (int nt = 0; nt < 4; ++nt)
      acc[mt][nt] = (f32x4){0.f, 0.f, 0.f, 0.f};

  for (int k0 = 0; k0 < NF; k0 += 32) {
    int kk = k0 + q8;
    bf16x8 af[2], bfr[4];
#pragma unroll
    for (int mt = 0; mt < 2; ++mt) {
      int f = fW + mt * 16 + l15;
      af[mt] = *(const bf16x8*)(WTr + f * 256 + kk);
    }
#pragma unroll
    for (int nt = 0; nt < 4; ++nt) {
      int i = iW + nt * 16 + l15;
      const float* p = hB + (size_t)i * NF + kk;
      bfr[nt] = cvt8(*(const float4*)p, *(const float4*)(p + 4));
    }
#pragma unroll
    for (int mt = 0; mt < 2; ++mt)
#pragma unroll
      for (int nt = 0; nt < 4; ++nt)
        acc[mt][nt] = __builtin_amdgcn_mfma_f32_16x16x32_bf16(af[mt], bfr[nt], acc[mt][nt], 0, 0, 0);
  }

  unsigned short* WhTb = WhT + (size_t)b * NF * NN;
  int q4 = (lane >> 4) * 4;
#pragma unroll
  for (int mt = 0; mt < 2; ++mt)
#pragma unroll
    for (int nt = 0; nt < 4; ++nt)
#pragma unroll
      for (int r = 0; r < 4; ++r) {
        int f = fW + mt * 16 + q4 + r;
        int i = iW + nt * 16 + l15;
        WhTb[(size_t)f * NN + i] = f2bf(acc[mt][nt][r]);
      }
}

// ---------------------------------------------------------------------------
// k_proj: Wh1[row] = h[row,:] . u ; Wh2[row] = h[row,:] . v  (wave per row, fp32)
// ---------------------------------------------------------------------------
__global__ __launch_bounds__(256) void k_proj(
    const float* __restrict__ h, const float* __restrict__ u,
    const float* __restrict__ v, float* __restrict__ Wh1, float* __restrict__ Wh2) {
  int row = blockIdx.x * 4 + (threadIdx.x >> 6);
  int lane = threadIdx.x & 63;
  float4 hv = *(const float4*)(h + (size_t)row * NF + lane * 4);
  const float* up = u + lane * 4;
  const float* vp = v + lane * 4;
  float su = hv.x * up[0] + hv.y * up[1] + hv.z * up[2] + hv.w * up[3];
  float sv = hv.x * vp[0] + hv.y * vp[1] + hv.z * vp[2] + hv.w * vp[3];
#pragma unroll
  for (int off = 32; off >= 1; off >>= 1) {
    su += __shfl_xor(su, off);
    sv += __shfl_xor(sv, off);
  }
  if (lane == 0) { Wh1[row] = su; Wh2[row] = sv; }
}

// ---------------------------------------------------------------------------
// k_soft: pure streaming masked-softmax, one wave per row (64 lanes x 32 elems).
// No LDS, 256-thread blocks (4 rows/block). ~68 us, near streaming roofline
// (268 MB adj+att at ~3.9 TB/s). grid 4096: rows 0..16383.
// ---------------------------------------------------------------------------
__global__ __launch_bounds__(256) void k_soft(
    const int* __restrict__ adj, const float* __restrict__ Wh1,
    const float* __restrict__ Wh2, float* __restrict__ att) {
  const float NEGBIG = -9.0e15f;
  int row = blockIdx.x * 4 + (threadIdx.x >> 6);  // global row 0..16383
  int lane = threadIdx.x & 63;
  int b = row >> 11;
  const float* w2 = Wh2 + (b << 11);
  const int* arow = adj + (size_t)row * NN;
  float w1 = Wh1[row];

  float x[32];
#pragma unroll
  for (int c = 0; c < 8; ++c) {
    int j = c * 256 + lane * 4;
    int4 av = *(const int4*)(arow + j);
    float4 pv = *(const float4*)(w2 + j);
    float t;
    t = w1 + pv.x; t = t >= 0.f ? t : 0.2f * t; x[c*4+0] = (av.x > 0) ? t : NEGBIG;
    t = w1 + pv.y; t = t >= 0.f ? t : 0.2f * t; x[c*4+1] = (av.y > 0) ? t : NEGBIG;
    t = w1 + pv.z; t = t >= 0.f ? t : 0.2f * t; x[c*4+2] = (av.z > 0) ? t : NEGBIG;
    t = w1 + pv.w; t = t >= 0.f ? t : 0.2f * t; x[c*4+3] = (av.w > 0) ? t : NEGBIG;
  }

  float m = x[0];
#pragma unroll
  for (int k = 1; k < 32; ++k) m = fmaxf(m, x[k]);
#pragma unroll
  for (int off = 32; off >= 1; off >>= 1) m = fmaxf(m, __shfl_xor(m, off));
  float sum = 0.f;
#pragma unroll
  for (int k = 0; k < 32; ++k) { x[k] = __expf(x[k] - m); sum += x[k]; }
#pragma unroll
  for (int off = 32; off >= 1; off >>= 1) sum += __shfl_xor(sum, off);
  float iv = 1.0f / sum;

  float* orow = att + (size_t)row * NN;
#pragma unroll
  for (int c = 0; c < 8; ++c) {
    int j = c * 256 + lane * 4;
    *(float4*)(orow + j) = make_float4(x[c*4+0] * iv, x[c*4+1] * iv,
                                       x[c*4+2] * iv, x[c*4+3] * iv);
  }
}

// ---------------------------------------------------------------------------
// k_pv: h_prime = att @ Wh, out = h + elu(h_prime).
// R6: NO LDS, NO BARRIER. Previous structure (stage 128KB fp32 att -> LDS,
//     syncthreads, GEMM) was barrier-coupled with only 2 blocks/CU (64KB LDS
//     cap); two rounds of evidence (occupancy-insensitive, pipelining-
//     insensitive, all pipes idle) point at the phase coupling, not per-load
//     latency. The MFMA A-fragment (lane 16g+l holds att[i0+l][kk+8g..+7])
//     is directly loadable from global fp32 att: 2x float4 + in-reg cvt8.
//     So: 256-thread blocks (4 waves), wave w owns f-stripe w*64 (4 MFMA
//     tiles), no staging phase at all. ~6 blocks/CU = 24 waves/CU of
//     free-running streaming GEMM; compiler pipelines with the freed VGPRs.
//     B pattern, XCD-affine swizzle (kept: FETCH 106->85 MB), epilogue
//     unchanged from the verified kernel.
// grid 1024: b(8) x itile(128,16i).
// ---------------------------------------------------------------------------
__global__ __launch_bounds__(256, 6) void k_pv(
    const float* __restrict__ attf, const unsigned short* __restrict__ WhT,
    const float* __restrict__ h, float* __restrict__ out) {
  int bx = blockIdx.x;
  bx = (bx & 7) * 128 + (bx >> 3);   // XCD-affine remap (bijective on [0,1024))
  int b = bx >> 7;
  int i0 = (bx & 127) * 16;
  int wave = threadIdx.x >> 6, lane = threadIdx.x & 63;
  int fW = wave * 64;
  int l15 = lane & 15, q8 = (lane >> 4) * 8;

  // A: lane reads att[b][i0+l15][kk+q8 .. +7] (fp32), cvt -> bf16 fragment
  const float* aBase = attf + ((size_t)(b * NN + i0 + l15)) * NN + q8;
  // B: lane reads WhT[b][fW+nt*16+l15][kk+q8 .. +7] (bf16)
  const unsigned short* bp = WhT + (size_t)b * NF * NN + (size_t)(fW + l15) * NN + q8;
  const size_t R16 = (size_t)16 * NN;

  f32x4 acc[4];
#pragma unroll
  for (int nt = 0; nt < 4; ++nt) acc[nt] = (f32x4){0.f, 0.f, 0.f, 0.f};

#pragma unroll 2
  for (int kk = 0; kk < NN; kk += 32) {
    float4 p0 = *(const float4*)(aBase + kk);
    float4 p1 = *(const float4*)(aBase + kk + 4);
    bf16x8 bfr[4];
#pragma unroll
    for (int nt = 0; nt < 4; ++nt)
      bfr[nt] = *(const bf16x8*)(bp + (size_t)nt * R16 + kk);
    bf16x8 afr = cvt8(p0, p1);
#pragma unroll
    for (int nt = 0; nt < 4; ++nt)
      acc[nt] = __builtin_amdgcn_mfma_f32_16x16x32_bf16(afr, bfr[nt], acc[nt], 0, 0, 0);
  }

  int q4 = (lane >> 4) * 4;
#pragma unroll
  for (int nt = 0; nt < 4; ++nt)
#pragma unroll
    for (int r = 0; r < 4; ++r) {
      int i = i0 + q4 + r;
      int f = fW + nt * 16 + l15;
      size_t idx = ((size_t)(b * NN + i)) * NF + f;
      float hp = acc[nt][r];
      float el = hp > 0.f ? hp : expm1f(hp);
      out[idx] = h[idx] + el;
    }
}

// ---------------------------------------------------------------------------
extern "C" void kernel_launch(void* const* d_in, const int* in_sizes, int n_in,
                              void* d_out, int out_size, void* d_ws, size_t ws_size,
                              hipStream_t stream) {
  // identify inputs by element count (all four are distinct)
  const float* h = nullptr; const int* adj = nullptr;
  const float* W = nullptr; const float* a = nullptr;
  for (int i = 0; i < n_in; ++i) {
    int s = in_sizes[i];
    if (s == NB * NN * NF) h = (const float*)d_in[i];
    else if (s == NB * NN * NN) adj = (const int*)d_in[i];
    else if (s == NF * NF) W = (const float*)d_in[i];
    else if (s == 2 * NF) a = (const float*)d_in[i];
  }

  float* out = (float*)d_out;                              // [8,2048,256] fp32
  float* att = out + (size_t)NB * NN * NF;                 // [8,2048,2048] fp32

  // ws footprint ~8.26 MB (proven safe)
  char* ws = (char*)d_ws;
  unsigned short* WhT = (unsigned short*)ws;               // 8 MB [8][256][2048] bf16
  unsigned short* WTr = (unsigned short*)(ws + 8388608);   // 128 KB [256][256] bf16
  float* u   = (float*)(ws + 8388608 + 131072);            // 1 KB
  float* v   = u + 256;                                    // 1 KB
  float* Wh1 = v + 256;                                    // 64 KB
  float* Wh2 = Wh1 + NB * NN;                              // 64 KB

  k_prep<<<257, 256, 0, stream>>>(W, a, WTr, u, v);
  k_wht<<<512, 256, 0, stream>>>(h, WTr, WhT);
  k_proj<<<NB * NN / 4, 256, 0, stream>>>(h, u, v, Wh1, Wh2);
  k_soft<<<NB * NN / 4, 256, 0, stream>>>(adj, Wh1, Wh2, att);
  k_pv<<<NB * 128, 256, 0, stream>>>(att, WhT, h, out);
}

// Round 7
// 412.936 us; speedup vs baseline: 1.1495x; 1.1495x over previous
//
#include <hip/hip_runtime.h>

#define NB 8
#define NN 2048
#define NF 256

typedef __attribute__((ext_vector_type(8))) short bf16x8;
typedef __attribute__((ext_vector_type(4))) float f32x4;

__device__ __forceinline__ unsigned short f2bf(float x) {
  union { float f; unsigned int i; } c; c.f = x;
  unsigned int r = c.i + 0x7FFFu + ((c.i >> 16) & 1u);
  return (unsigned short)(r >> 16);
}
// round-half-up bf16 (1 add + 1 shift) — hot convert paths
__device__ __forceinline__ unsigned short f2bf_fast(float x) {
  union { float f; unsigned int i; } c; c.f = x;
  return (unsigned short)((c.i + 0x8000u) >> 16);
}
__device__ __forceinline__ bf16x8 cvt8(float4 c0, float4 c1) {
  union { bf16x8 v8; unsigned short us[8]; } cu;
  cu.us[0] = f2bf_fast(c0.x); cu.us[1] = f2bf_fast(c0.y);
  cu.us[2] = f2bf_fast(c0.z); cu.us[3] = f2bf_fast(c0.w);
  cu.us[4] = f2bf_fast(c1.x); cu.us[5] = f2bf_fast(c1.y);
  cu.us[6] = f2bf_fast(c1.z); cu.us[7] = f2bf_fast(c1.w);
  return cu.v8;
}

// ---------------------------------------------------------------------------
// k_prep: WT[f][k] = bf16(W[k][f]);  u = W @ a1, v = W @ a2  (fp32)
// ---------------------------------------------------------------------------
__global__ __launch_bounds__(256) void k_prep(
    const float* __restrict__ W, const float* __restrict__ a,
    unsigned short* __restrict__ WT, float* __restrict__ u, float* __restrict__ v) {
  int t = threadIdx.x;
  if (blockIdx.x < 256) {
    int k = blockIdx.x;
    WT[t * 256 + k] = f2bf(W[k * 256 + t]);
  } else {
    float su = 0.f, sv = 0.f;
    for (int o = 0; o < 256; ++o) {
      float w = W[t * 256 + o];
      su += w * a[o];
      sv += w * a[256 + o];
    }
    u[t] = su; v[t] = sv;
  }
}

// ---------------------------------------------------------------------------
// k_mid: merges old k_wht + k_proj (independent work, both depend only on
// k_prep) into ONE launch — fewer serialized launches, and both fill the GPU
// together.
// Blocks [0,256): WhT[b][f][i] = sum_k W[k][f]*h[b][i][k].
//   NEW TILING: 64-row i-tiles, wave = 16 rows x all 256 f (16 MFMA tiles,
//   acc=64 VGPR). h is read EXACTLY ONCE (64 MB total; old tiling re-read it
//   4x = 256 MB). WTr panel (128 KB) is L1/L2-hot, re-read per wave.
// Blocks [256, 256+4096): Wh1[row]=h[row,:].u, Wh2=h.v (wave per row, fp32) —
//   old k_proj body unchanged.
// ---------------------------------------------------------------------------
__global__ __launch_bounds__(256) void k_mid(
    const float* __restrict__ h, const unsigned short* __restrict__ WTr,
    const float* __restrict__ u, const float* __restrict__ v,
    unsigned short* __restrict__ WhT, float* __restrict__ Wh1, float* __restrict__ Wh2) {
  int bx = blockIdx.x;
  if (bx < 256) {
    int b = bx >> 5;
    int i64 = (bx & 31) * 64;
    int wave = threadIdx.x >> 6, lane = threadIdx.x & 63;
    int iW = i64 + wave * 16;              // this wave's 16 i-rows
    int l15 = lane & 15, q8 = (lane >> 4) * 8;
    const float* hB = h + (size_t)b * NN * NF;

    f32x4 acc[16];
#pragma unroll
    for (int ft = 0; ft < 16; ++ft) acc[ft] = (f32x4){0.f, 0.f, 0.f, 0.f};

    for (int k0 = 0; k0 < NF; k0 += 32) {
      int kk = k0 + q8;
      const float* p = hB + (size_t)(iW + l15) * NF + kk;
      bf16x8 bfr = cvt8(*(const float4*)p, *(const float4*)(p + 4));
#pragma unroll
      for (int ft = 0; ft < 16; ++ft) {
        bf16x8 af = *(const bf16x8*)(WTr + (ft * 16 + l15) * 256 + kk);
        acc[ft] = __builtin_amdgcn_mfma_f32_16x16x32_bf16(af, bfr, acc[ft], 0, 0, 0);
      }
    }

    unsigned short* WhTb = WhT + (size_t)b * NF * NN;
    int q4 = (lane >> 4) * 4;
#pragma unroll
    for (int ft = 0; ft < 16; ++ft)
#pragma unroll
      for (int r = 0; r < 4; ++r) {
        int f = ft * 16 + q4 + r;
        int i = iW + l15;
        WhTb[(size_t)f * NN + i] = f2bf(acc[ft][r]);
      }
  } else {
    int row = (bx - 256) * 4 + (threadIdx.x >> 6);
    int lane = threadIdx.x & 63;
    float4 hv = *(const float4*)(h + (size_t)row * NF + lane * 4);
    const float* up = u + lane * 4;
    const float* vp = v + lane * 4;
    float su = hv.x * up[0] + hv.y * up[1] + hv.z * up[2] + hv.w * up[3];
    float sv = hv.x * vp[0] + hv.y * vp[1] + hv.z * vp[2] + hv.w * vp[3];
#pragma unroll
    for (int off = 32; off >= 1; off >>= 1) {
      su += __shfl_xor(su, off);
      sv += __shfl_xor(sv, off);
    }
    if (lane == 0) { Wh1[row] = su; Wh2[row] = sv; }
  }
}

// ---------------------------------------------------------------------------
// k_fuse: softmax (16 rows) + att@WhT + h+elu epilogue, one block per row-tile.
// FUSED structure restored (best measured total: 397 us in R2; the k_soft/k_pv
// split costs a 134 MB att fp32 re-read + a launch). One change vs R2/R3:
// XCD-affine blockIdx swizzle — XCD x gets all 128 blocks of batch x, so its
// 1 MB WhT B-panel stays L2-resident (proven on split k_pv: FETCH 106->85 MB).
// Phase 1: wave handles 2 rows one at a time (x[32] live); fp32 att to global,
//          normalized bf16 att into XOR-swizzled LDS (swz = row*8).
// Phase 2: GEMM 16i x 256f x 2048j; wave owns a 32-wide f-stripe; A from LDS
//          ds_read_b128 (swizzled, conflict-free), B = WhT 16B frags (L2);
//          fused out = h + elu.
// grid 1024: b(8) x itile(128,16i); 512 thr / 8 waves; LDS 64 KB.
// ---------------------------------------------------------------------------
__global__ __launch_bounds__(512, 4) void k_fuse(
    const int* __restrict__ adj, const float* __restrict__ Wh1,
    const float* __restrict__ Wh2, const unsigned short* __restrict__ WhT,
    const float* __restrict__ h, float* __restrict__ att, float* __restrict__ out) {
  __shared__ unsigned short satt[16 * 2048];  // 64 KB, XOR-swizzled rows
  const float NEGBIG = -9.0e15f;
  int bx = blockIdx.x;
  bx = (bx & 7) * 128 + (bx >> 3);   // XCD-affine remap (bijective on [0,1024))
  int b = bx >> 7;
  int i0 = (bx & 127) * 16;
  int wave = threadIdx.x >> 6, lane = threadIdx.x & 63;
  const float* w2 = Wh2 + ((size_t)b << 11);

  // ---------------- phase 1: masked-softmax, one row at a time -------------
  int rowbase = b * NN + i0 + wave * 2;
#pragma unroll
  for (int rr = 0; rr < 2; ++rr) {
    const int* arow = adj + (size_t)(rowbase + rr) * NN;
    float w1 = Wh1[rowbase + rr];
    float x[32];
#pragma unroll
    for (int c = 0; c < 8; ++c) {
      int j = c * 256 + lane * 4;
      int4 av = *(const int4*)(arow + j);
      float4 pv = *(const float4*)(w2 + j);
      float t;
      t = w1 + pv.x; t = t >= 0.f ? t : 0.2f * t; x[c*4+0] = (av.x > 0) ? t : NEGBIG;
      t = w1 + pv.y; t = t >= 0.f ? t : 0.2f * t; x[c*4+1] = (av.y > 0) ? t : NEGBIG;
      t = w1 + pv.z; t = t >= 0.f ? t : 0.2f * t; x[c*4+2] = (av.z > 0) ? t : NEGBIG;
      t = w1 + pv.w; t = t >= 0.f ? t : 0.2f * t; x[c*4+3] = (av.w > 0) ? t : NEGBIG;
    }

    float m = x[0];
#pragma unroll
    for (int k = 1; k < 32; ++k) m = fmaxf(m, x[k]);
#pragma unroll
    for (int off = 32; off >= 1; off >>= 1) m = fmaxf(m, __shfl_xor(m, off));
    float sum = 0.f;
#pragma unroll
    for (int k = 0; k < 32; ++k) { x[k] = __expf(x[k] - m); sum += x[k]; }
#pragma unroll
    for (int off = 32; off >= 1; off >>= 1) sum += __shfl_xor(sum, off);
    float iv = 1.0f / sum;

    int row_local = wave * 2 + rr;
    int swz = row_local * 8;
    float* orow = att + (size_t)(rowbase + rr) * NN;
    unsigned short* srow = satt + row_local * 2048;
#pragma unroll
    for (int c = 0; c < 8; ++c) {
      int j = c * 256 + lane * 4;
      float a0 = x[c*4+0] * iv, a1 = x[c*4+1] * iv;
      float a2 = x[c*4+2] * iv, a3 = x[c*4+3] * iv;
      *(float4*)(orow + j) = make_float4(a0, a1, a2, a3);
      // LDS: 4 bf16 (8B) at swizzled offset; groups of 8 permuted by swz
      int e = ((j & ~7) ^ swz) + (j & 7);
      union { short4 v4; unsigned short us[4]; } pk;
      pk.us[0] = f2bf_fast(a0); pk.us[1] = f2bf_fast(a1);
      pk.us[2] = f2bf_fast(a2); pk.us[3] = f2bf_fast(a3);
      *(short4*)(srow + e) = pk.v4;
    }
  }

  __syncthreads();

  // ---------------- phase 2: h_prime = att @ Wh, out = h + elu -------------
  int fW = wave * 32;
  int l15 = lane & 15, q8 = (lane >> 4) * 8;
  const unsigned short* WTb = WhT + (size_t)b * NF * NN;
  const unsigned short* aRow = satt + l15 * 2048;
  int swzA = l15 * 8;

  f32x4 acc[2];
#pragma unroll
  for (int nt = 0; nt < 2; ++nt) acc[nt] = (f32x4){0.f, 0.f, 0.f, 0.f};

  for (int kk = 0; kk < NN; kk += 32) {
    bf16x8 afr = *(const bf16x8*)(aRow + (((kk + q8) ^ swzA)));
    bf16x8 bfr[2];
#pragma unroll
    for (int nt = 0; nt < 2; ++nt) {
      int f = fW + nt * 16 + l15;
      bfr[nt] = *(const bf16x8*)(WTb + (size_t)f * NN + kk + q8);
    }
#pragma unroll
    for (int nt = 0; nt < 2; ++nt)
      acc[nt] = __builtin_amdgcn_mfma_f32_16x16x32_bf16(afr, bfr[nt], acc[nt], 0, 0, 0);
  }

  int q4 = (lane >> 4) * 4;
#pragma unroll
  for (int nt = 0; nt < 2; ++nt)
#pragma unroll
    for (int r = 0; r < 4; ++r) {
      int i = i0 + q4 + r;
      int f = fW + nt * 16 + l15;
      size_t idx = ((size_t)(b * NN + i)) * NF + f;
      float hp = acc[nt][r];
      float el = hp > 0.f ? hp : expm1f(hp);
      out[idx] = h[idx] + el;
    }
}

// ---------------------------------------------------------------------------
extern "C" void kernel_launch(void* const* d_in, const int* in_sizes, int n_in,
                              void* d_out, int out_size, void* d_ws, size_t ws_size,
                              hipStream_t stream) {
  // identify inputs by element count (all four are distinct)
  const float* h = nullptr; const int* adj = nullptr;
  const float* W = nullptr; const float* a = nullptr;
  for (int i = 0; i < n_in; ++i) {
    int s = in_sizes[i];
    if (s == NB * NN * NF) h = (const float*)d_in[i];
    else if (s == NB * NN * NN) adj = (const int*)d_in[i];
    else if (s == NF * NF) W = (const float*)d_in[i];
    else if (s == 2 * NF) a = (const float*)d_in[i];
  }

  float* out = (float*)d_out;                              // [8,2048,256] fp32
  float* att = out + (size_t)NB * NN * NF;                 // [8,2048,2048] fp32

  // ws footprint ~8.26 MB (proven safe)
  char* ws = (char*)d_ws;
  unsigned short* WhT = (unsigned short*)ws;               // 8 MB [8][256][2048] bf16
  unsigned short* WTr = (unsigned short*)(ws + 8388608);   // 128 KB [256][256] bf16
  float* u   = (float*)(ws + 8388608 + 131072);            // 1 KB
  float* v   = u + 256;                                    // 1 KB
  float* Wh1 = v + 256;                                    // 64 KB
  float* Wh2 = Wh1 + NB * NN;                              // 64 KB

  k_prep<<<257, 256, 0, stream>>>(W, a, WTr, u, v);
  k_mid<<<256 + NB * NN / 4, 256, 0, stream>>>(h, WTr, u, v, WhT, Wh1, Wh2);
  k_fuse<<<NB * 128, 512, 0, stream>>>(adj, Wh1, Wh2, WhT, h, att, out);
}

// Round 8
// 406.663 us; speedup vs baseline: 1.1672x; 1.0154x over previous
//
#include <hip/hip_runtime.h>

#define NB 8
#define NN 2048
#define NF 256

typedef __attribute__((ext_vector_type(8))) short bf16x8;
typedef __attribute__((ext_vector_type(4))) float f32x4;
typedef __attribute__((ext_vector_type(4))) int i32x4;

__device__ __forceinline__ unsigned short f2bf(float x) {
  union { float f; unsigned int i; } c; c.f = x;
  unsigned int r = c.i + 0x7FFFu + ((c.i >> 16) & 1u);
  return (unsigned short)(r >> 16);
}
// round-half-up bf16 (1 add + 1 shift) — hot convert paths
__device__ __forceinline__ unsigned short f2bf_fast(float x) {
  union { float f; unsigned int i; } c; c.f = x;
  return (unsigned short)((c.i + 0x8000u) >> 16);
}
__device__ __forceinline__ bf16x8 cvt8(float4 c0, float4 c1) {
  union { bf16x8 v8; unsigned short us[8]; } cu;
  cu.us[0] = f2bf_fast(c0.x); cu.us[1] = f2bf_fast(c0.y);
  cu.us[2] = f2bf_fast(c0.z); cu.us[3] = f2bf_fast(c0.w);
  cu.us[4] = f2bf_fast(c1.x); cu.us[5] = f2bf_fast(c1.y);
  cu.us[6] = f2bf_fast(c1.z); cu.us[7] = f2bf_fast(c1.w);
  return cu.v8;
}
__device__ __forceinline__ bf16x8 cvt8v(f32x4 c0, f32x4 c1) {
  union { bf16x8 v8; unsigned short us[8]; } cu;
  cu.us[0] = f2bf_fast(c0.x); cu.us[1] = f2bf_fast(c0.y);
  cu.us[2] = f2bf_fast(c0.z); cu.us[3] = f2bf_fast(c0.w);
  cu.us[4] = f2bf_fast(c1.x); cu.us[5] = f2bf_fast(c1.y);
  cu.us[6] = f2bf_fast(c1.z); cu.us[7] = f2bf_fast(c1.w);
  return cu.v8;
}

// ---------------------------------------------------------------------------
// k_prep: WT[f][k] = bf16(W[k][f]);  u = W @ a1, v = W @ a2  (fp32)
// ---------------------------------------------------------------------------
__global__ __launch_bounds__(256) void k_prep(
    const float* __restrict__ W, const float* __restrict__ a,
    unsigned short* __restrict__ WT, float* __restrict__ u, float* __restrict__ v) {
  int t = threadIdx.x;
  if (blockIdx.x < 256) {
    int k = blockIdx.x;
    WT[t * 256 + k] = f2bf(W[k * 256 + t]);
  } else {
    float su = 0.f, sv = 0.f;
    for (int o = 0; o < 256; ++o) {
      float w = W[t * 256 + o];
      su += w * a[o];
      sv += w * a[256 + o];
    }
    u[t] = su; v[t] = sv;
  }
}

// ---------------------------------------------------------------------------
// k_mid: WhT[b][f][i] = sum_k W[k][f]*h[b][i][k]  AND  Wh1/Wh2 = h.u / h.v,
// fused into one pass over h (h read exactly once from HBM).
// grid 1024: b(8) x itile(128,16 rows). 4 waves x 64f; acc[4] (16 VGPR) ->
// high occupancy (old k_mid used 256 blocks = 1/CU, 1 wave/SIMD, latency-
// exposed). All 4 waves read the same 16 h-rows (L1-dedup); wave 0 also
// accumulates the u/v dot products and writes Wh1/Wh2 (replaces k_proj's
// separate 64 MB h re-read).
// ---------------------------------------------------------------------------
__global__ __launch_bounds__(256) void k_mid(
    const float* __restrict__ h, const unsigned short* __restrict__ WTr,
    const float* __restrict__ u, const float* __restrict__ v,
    unsigned short* __restrict__ WhT, float* __restrict__ Wh1, float* __restrict__ Wh2) {
  int bx = blockIdx.x;
  int b = bx >> 7;
  int iW = (bx & 127) * 16;
  int wave = threadIdx.x >> 6, lane = threadIdx.x & 63;
  int fW = wave * 64;
  int l15 = lane & 15, q8 = (lane >> 4) * 8;
  const float* hB = h + (size_t)b * NN * NF;

  f32x4 acc[4];
#pragma unroll
  for (int ft = 0; ft < 4; ++ft) acc[ft] = (f32x4){0.f, 0.f, 0.f, 0.f};
  float su = 0.f, sv = 0.f;

  for (int k0 = 0; k0 < NF; k0 += 32) {
    int kk = k0 + q8;
    const float* p = hB + (size_t)(iW + l15) * NF + kk;
    float4 h0 = *(const float4*)p;
    float4 h1 = *(const float4*)(p + 4);
    bf16x8 bfr = cvt8(h0, h1);
    if (wave == 0) {
      const float* up = u + kk;
      const float* vp = v + kk;
      su += h0.x*up[0] + h0.y*up[1] + h0.z*up[2] + h0.w*up[3]
          + h1.x*up[4] + h1.y*up[5] + h1.z*up[6] + h1.w*up[7];
      sv += h0.x*vp[0] + h0.y*vp[1] + h0.z*vp[2] + h0.w*vp[3]
          + h1.x*vp[4] + h1.y*vp[5] + h1.z*vp[6] + h1.w*vp[7];
    }
#pragma unroll
    for (int ft = 0; ft < 4; ++ft) {
      bf16x8 af = *(const bf16x8*)(WTr + (fW + ft * 16 + l15) * 256 + kk);
      acc[ft] = __builtin_amdgcn_mfma_f32_16x16x32_bf16(af, bfr, acc[ft], 0, 0, 0);
    }
  }

  unsigned short* WhTb = WhT + (size_t)b * NF * NN;
  int q4 = (lane >> 4) * 4;
#pragma unroll
  for (int ft = 0; ft < 4; ++ft)
#pragma unroll
    for (int r = 0; r < 4; ++r) {
      int f = fW + ft * 16 + q4 + r;
      WhTb[(size_t)f * NN + iW + l15] = f2bf(acc[ft][r]);
    }

  if (wave == 0) {
    // lanes {l15, l15+16, l15+32, l15+48} hold disjoint k-slices of row iW+l15
    su += __shfl_xor(su, 16); su += __shfl_xor(su, 32);
    sv += __shfl_xor(sv, 16); sv += __shfl_xor(sv, 32);
    if (lane < 16) {
      Wh1[b * NN + iW + lane] = su;
      Wh2[b * NN + iW + lane] = sv;
    }
  }
}

// ---------------------------------------------------------------------------
// k_fuse: softmax (16 rows) + att@WhT + h+elu epilogue, one block per row-tile.
// R8 change (single, surgical): NON-TEMPORAL loads/stores on the zero-reuse
// streams — adj reads (134 MB), att writes (134 MB), epilogue h reads / out
// writes. Theory: these streams thrash the 4 MB per-XCD L2, evicting the 1 MB
// WhT B-panel that phase 2 of co-resident blocks re-reads 128x, turning every
// B load into an L3-latency miss (~600cy). That fits ALL evidence: every pipe
// idle, occupancy-insensitive (R2), reg-pipelining-insensitive (R5). nt =
// evict-first, keeps L2 for WhT. Everything else byte-identical to R7.
// grid 1024: b(8) x itile(128,16i); 512 thr / 8 waves; LDS 64 KB.
// ---------------------------------------------------------------------------
__global__ __launch_bounds__(512, 4) void k_fuse(
    const int* __restrict__ adj, const float* __restrict__ Wh1,
    const float* __restrict__ Wh2, const unsigned short* __restrict__ WhT,
    const float* __restrict__ h, float* __restrict__ att, float* __restrict__ out) {
  __shared__ unsigned short satt[16 * 2048];  // 64 KB, XOR-swizzled rows
  const float NEGBIG = -9.0e15f;
  int bx = blockIdx.x;
  bx = (bx & 7) * 128 + (bx >> 3);   // XCD-affine remap (bijective on [0,1024))
  int b = bx >> 7;
  int i0 = (bx & 127) * 16;
  int wave = threadIdx.x >> 6, lane = threadIdx.x & 63;
  const float* w2 = Wh2 + ((size_t)b << 11);

  // ---------------- phase 1: masked-softmax, one row at a time -------------
  int rowbase = b * NN + i0 + wave * 2;
#pragma unroll
  for (int rr = 0; rr < 2; ++rr) {
    const int* arow = adj + (size_t)(rowbase + rr) * NN;
    float w1 = Wh1[rowbase + rr];
    float x[32];
#pragma unroll
    for (int c = 0; c < 8; ++c) {
      int j = c * 256 + lane * 4;
      i32x4 av = __builtin_nontemporal_load((const i32x4*)(arow + j));
      float4 pv = *(const float4*)(w2 + j);
      float t;
      t = w1 + pv.x; t = t >= 0.f ? t : 0.2f * t; x[c*4+0] = (av.x > 0) ? t : NEGBIG;
      t = w1 + pv.y; t = t >= 0.f ? t : 0.2f * t; x[c*4+1] = (av.y > 0) ? t : NEGBIG;
      t = w1 + pv.z; t = t >= 0.f ? t : 0.2f * t; x[c*4+2] = (av.z > 0) ? t : NEGBIG;
      t = w1 + pv.w; t = t >= 0.f ? t : 0.2f * t; x[c*4+3] = (av.w > 0) ? t : NEGBIG;
    }

    float m = x[0];
#pragma unroll
    for (int k = 1; k < 32; ++k) m = fmaxf(m, x[k]);
#pragma unroll
    for (int off = 32; off >= 1; off >>= 1) m = fmaxf(m, __shfl_xor(m, off));
    float sum = 0.f;
#pragma unroll
    for (int k = 0; k < 32; ++k) { x[k] = __expf(x[k] - m); sum += x[k]; }
#pragma unroll
    for (int off = 32; off >= 1; off >>= 1) sum += __shfl_xor(sum, off);
    float iv = 1.0f / sum;

    int row_local = wave * 2 + rr;
    int swz = row_local * 8;
    float* orow = att + (size_t)(rowbase + rr) * NN;
    unsigned short* srow = satt + row_local * 2048;
#pragma unroll
    for (int c = 0; c < 8; ++c) {
      int j = c * 256 + lane * 4;
      float a0 = x[c*4+0] * iv, a1 = x[c*4+1] * iv;
      float a2 = x[c*4+2] * iv, a3 = x[c*4+3] * iv;
      f32x4 ov = (f32x4){a0, a1, a2, a3};
      __builtin_nontemporal_store(ov, (f32x4*)(orow + j));
      // LDS: 4 bf16 (8B) at swizzled offset; groups of 8 permuted by swz
      int e = ((j & ~7) ^ swz) + (j & 7);
      union { short4 v4; unsigned short us[4]; } pk;
      pk.us[0] = f2bf_fast(a0); pk.us[1] = f2bf_fast(a1);
      pk.us[2] = f2bf_fast(a2); pk.us[3] = f2bf_fast(a3);
      *(short4*)(srow + e) = pk.v4;
    }
  }

  __syncthreads();

  // ---------------- phase 2: h_prime = att @ Wh, out = h + elu -------------
  int fW = wave * 32;
  int l15 = lane & 15, q8 = (lane >> 4) * 8;
  const unsigned short* WTb = WhT + (size_t)b * NF * NN;
  const unsigned short* aRow = satt + l15 * 2048;
  int swzA = l15 * 8;

  f32x4 acc[2];
#pragma unroll
  for (int nt = 0; nt < 2; ++nt) acc[nt] = (f32x4){0.f, 0.f, 0.f, 0.f};

  for (int kk = 0; kk < NN; kk += 32) {
    bf16x8 afr = *(const bf16x8*)(aRow + (((kk + q8) ^ swzA)));
    bf16x8 bfr[2];
#pragma unroll
    for (int nt = 0; nt < 2; ++nt) {
      int f = fW + nt * 16 + l15;
      bfr[nt] = *(const bf16x8*)(WTb + (size_t)f * NN + kk + q8);
    }
#pragma unroll
    for (int nt = 0; nt < 2; ++nt)
      acc[nt] = __builtin_amdgcn_mfma_f32_16x16x32_bf16(afr, bfr[nt], acc[nt], 0, 0, 0);
  }

  int q4 = (lane >> 4) * 4;
#pragma unroll
  for (int nt = 0; nt < 2; ++nt)
#pragma unroll
    for (int r = 0; r < 4; ++r) {
      int i = i0 + q4 + r;
      int f = fW + nt * 16 + l15;
      size_t idx = ((size_t)(b * NN + i)) * NF + f;
      float hp = acc[nt][r];
      float el = hp > 0.f ? hp : expm1f(hp);
      float hv = __builtin_nontemporal_load(h + idx);
      __builtin_nontemporal_store(hv + el, out + idx);
    }
}

// ---------------------------------------------------------------------------
extern "C" void kernel_launch(void* const* d_in, const int* in_sizes, int n_in,
                              void* d_out, int out_size, void* d_ws, size_t ws_size,
                              hipStream_t stream) {
  // identify inputs by element count (all four are distinct)
  const float* h = nullptr; const int* adj = nullptr;
  const float* W = nullptr; const float* a = nullptr;
  for (int i = 0; i < n_in; ++i) {
    int s = in_sizes[i];
    if (s == NB * NN * NF) h = (const float*)d_in[i];
    else if (s == NB * NN * NN) adj = (const int*)d_in[i];
    else if (s == NF * NF) W = (const float*)d_in[i];
    else if (s == 2 * NF) a = (const float*)d_in[i];
  }

  float* out = (float*)d_out;                              // [8,2048,256] fp32
  float* att = out + (size_t)NB * NN * NF;                 // [8,2048,2048] fp32

  // ws footprint ~8.26 MB (proven safe)
  char* ws = (char*)d_ws;
  unsigned short* WhT = (unsigned short*)ws;               // 8 MB [8][256][2048] bf16
  unsigned short* WTr = (unsigned short*)(ws + 8388608);   // 128 KB [256][256] bf16
  float* u   = (float*)(ws + 8388608 + 131072);            // 1 KB
  float* v   = u + 256;                                    // 1 KB
  float* Wh1 = v + 256;                                    // 64 KB
  float* Wh2 = Wh1 + NB * NN;                              // 64 KB

  k_prep<<<257, 256, 0, stream>>>(W, a, WTr, u, v);
  k_mid<<<1024, 256, 0, stream>>>(h, WTr, u, v, WhT, Wh1, Wh2);
  k_fuse<<<NB * 128, 512, 0, stream>>>(adj, Wh1, Wh2, WhT, h, att, out);
}

// Round 9
// 347.268 us; speedup vs baseline: 1.3669x; 1.1710x over previous
//
#include <hip/hip_runtime.h>

#define NB 8
#define NN 2048
#define NF 256

typedef __attribute__((ext_vector_type(8))) short bf16x8;
typedef __attribute__((ext_vector_type(4))) float f32x4;
typedef __attribute__((ext_vector_type(4))) int i32x4;

// Fragment-ordered panel layout ("frag order"):
//   blob[kb][f][g][j]  (shorts)  kb=k/32, g=lane>>4 (k-octet), j=k&7
//   addr_sh = kb*8192 + f*32 + g*8 + j
// A wave's MFMA B-fragment load (rows f..f+15, k-octet per lane-quad) is then
// ONE contiguous 1KB load. The old [f][k] layout made every fragment load a
// 16-segment gather (lanes 0..15 hit rows 4KB apart) - ~16x the VMEM
// transaction slots; this was the invisible time sink (no counter shows it).

__device__ __forceinline__ unsigned short f2bf(float x) {
  union { float f; unsigned int i; } c; c.f = x;
  unsigned int r = c.i + 0x7FFFu + ((c.i >> 16) & 1u);
  return (unsigned short)(r >> 16);
}
// round-half-up bf16 (1 add + 1 shift) — hot convert paths
__device__ __forceinline__ unsigned short f2bf_fast(float x) {
  union { float f; unsigned int i; } c; c.f = x;
  return (unsigned short)((c.i + 0x8000u) >> 16);
}
__device__ __forceinline__ bf16x8 cvt8(float4 c0, float4 c1) {
  union { bf16x8 v8; unsigned short us[8]; } cu;
  cu.us[0] = f2bf_fast(c0.x); cu.us[1] = f2bf_fast(c0.y);
  cu.us[2] = f2bf_fast(c0.z); cu.us[3] = f2bf_fast(c0.w);
  cu.us[4] = f2bf_fast(c1.x); cu.us[5] = f2bf_fast(c1.y);
  cu.us[6] = f2bf_fast(c1.z); cu.us[7] = f2bf_fast(c1.w);
  return cu.v8;
}

// ---------------------------------------------------------------------------
// k_prep: WTr_frag[k/32][f][g][j] = bf16(W[k][f]);  u = W@a1, v = W@a2 (fp32)
// ---------------------------------------------------------------------------
__global__ __launch_bounds__(256) void k_prep(
    const float* __restrict__ W, const float* __restrict__ a,
    unsigned short* __restrict__ WT, float* __restrict__ u, float* __restrict__ v) {
  int t = threadIdx.x;
  if (blockIdx.x < 256) {
    int k = blockIdx.x;
    // frag-order: kb=k>>5, f=t, g=(k>>3)&3, j=k&7
    WT[(k >> 5) * 8192 + t * 32 + ((k >> 3) & 3) * 8 + (k & 7)] = f2bf(W[k * 256 + t]);
  } else {
    float su = 0.f, sv = 0.f;
    for (int o = 0; o < 256; ++o) {
      float w = W[t * 256 + o];
      su += w * a[o];
      sv += w * a[256 + o];
    }
    u[t] = su; v[t] = sv;
  }
}

// ---------------------------------------------------------------------------
// k_mid: WhT_frag = W^T h^T (frag-order) AND Wh1/Wh2 = h.u / h.v, one h pass.
// grid 1024: b(8) x itile(128,16 rows). 4 waves x 64f; acc[4].
// WTr is read in frag-order (coalesced 1KB fragment loads; was 16-seg gather).
// WhT written in frag-order for k_fuse phase 2.
// ---------------------------------------------------------------------------
__global__ __launch_bounds__(256) void k_mid(
    const float* __restrict__ h, const unsigned short* __restrict__ WTr,
    const float* __restrict__ u, const float* __restrict__ v,
    unsigned short* __restrict__ WhT, float* __restrict__ Wh1, float* __restrict__ Wh2) {
  int bx = blockIdx.x;
  int b = bx >> 7;
  int iW = (bx & 127) * 16;
  int wave = threadIdx.x >> 6, lane = threadIdx.x & 63;
  int fW = wave * 64;
  int l15 = lane & 15, gq = lane >> 4, q8 = gq * 8;
  const float* hB = h + (size_t)b * NN * NF;

  f32x4 acc[4];
#pragma unroll
  for (int ft = 0; ft < 4; ++ft) acc[ft] = (f32x4){0.f, 0.f, 0.f, 0.f};
  float su = 0.f, sv = 0.f;

  // frag-order af base: rows fW+ft*16+l15, k-octet gq
  const unsigned short* wf = WTr + (fW + l15) * 32 + gq * 8;

  for (int k0 = 0; k0 < NF; k0 += 32) {
    int kk = k0 + q8;
    const float* p = hB + (size_t)(iW + l15) * NF + kk;
    float4 h0 = *(const float4*)p;
    float4 h1 = *(const float4*)(p + 4);
    bf16x8 bfr = cvt8(h0, h1);
    if (wave == 0) {
      const float* up = u + kk;
      const float* vp = v + kk;
      su += h0.x*up[0] + h0.y*up[1] + h0.z*up[2] + h0.w*up[3]
          + h1.x*up[4] + h1.y*up[5] + h1.z*up[6] + h1.w*up[7];
      sv += h0.x*vp[0] + h0.y*vp[1] + h0.z*vp[2] + h0.w*vp[3]
          + h1.x*vp[4] + h1.y*vp[5] + h1.z*vp[6] + h1.w*vp[7];
    }
    const unsigned short* wk = wf + (k0 >> 5) * 8192;
#pragma unroll
    for (int ft = 0; ft < 4; ++ft) {
      bf16x8 af = *(const bf16x8*)(wk + ft * 512);   // 16 rows x 32 sh
      acc[ft] = __builtin_amdgcn_mfma_f32_16x16x32_bf16(af, bfr, acc[ft], 0, 0, 0);
    }
  }

  // frag-order WhT write: k-dim of phase2 is i here.
  unsigned short* WhTb = WhT + (size_t)b * NF * NN;
  int kb = iW >> 5;
  int gg = ((iW & 16) + l15) >> 3;
  int jj = l15 & 7;
  int q4 = gq * 4;
#pragma unroll
  for (int ft = 0; ft < 4; ++ft)
#pragma unroll
    for (int r = 0; r < 4; ++r) {
      int f = fW + ft * 16 + q4 + r;
      WhTb[kb * 8192 + f * 32 + gg * 8 + jj] = f2bf(acc[ft][r]);
    }

  if (wave == 0) {
    // lanes {l15, l15+16, l15+32, l15+48} hold disjoint k-slices of row iW+l15
    su += __shfl_xor(su, 16); su += __shfl_xor(su, 32);
    sv += __shfl_xor(sv, 16); sv += __shfl_xor(sv, 32);
    if (lane < 16) {
      Wh1[b * NN + iW + lane] = su;
      Wh2[b * NN + iW + lane] = sv;
    }
  }
}

// ---------------------------------------------------------------------------
// k_fuse: softmax (16 rows) + att@WhT + h+elu epilogue, one block per row-tile.
// R9 change: phase-2 B loads read WhT in FRAG-ORDER — each fragment is one
// contiguous 1KB wave-load (was a 16-row x 4KB-stride gather = 16 segments
// per instruction, ~16x VMEM transaction slots; fits all prior null results:
// occupancy-insensitive, MLP-insensitive, all pipes "idle").
// Keeps: XCD-affine swizzle, nt loads/stores on zero-reuse streams (R8).
// grid 1024: b(8) x itile(128,16i); 512 thr / 8 waves; LDS 64 KB.
// ---------------------------------------------------------------------------
__global__ __launch_bounds__(512, 4) void k_fuse(
    const int* __restrict__ adj, const float* __restrict__ Wh1,
    const float* __restrict__ Wh2, const unsigned short* __restrict__ WhT,
    const float* __restrict__ h, float* __restrict__ att, float* __restrict__ out) {
  __shared__ unsigned short satt[16 * 2048];  // 64 KB, XOR-swizzled rows
  const float NEGBIG = -9.0e15f;
  int bx = blockIdx.x;
  bx = (bx & 7) * 128 + (bx >> 3);   // XCD-affine remap (bijective on [0,1024))
  int b = bx >> 7;
  int i0 = (bx & 127) * 16;
  int wave = threadIdx.x >> 6, lane = threadIdx.x & 63;
  const float* w2 = Wh2 + ((size_t)b << 11);

  // ---------------- phase 1: masked-softmax, one row at a time -------------
  int rowbase = b * NN + i0 + wave * 2;
#pragma unroll
  for (int rr = 0; rr < 2; ++rr) {
    const int* arow = adj + (size_t)(rowbase + rr) * NN;
    float w1 = Wh1[rowbase + rr];
    float x[32];
#pragma unroll
    for (int c = 0; c < 8; ++c) {
      int j = c * 256 + lane * 4;
      i32x4 av = __builtin_nontemporal_load((const i32x4*)(arow + j));
      float4 pv = *(const float4*)(w2 + j);
      float t;
      t = w1 + pv.x; t = t >= 0.f ? t : 0.2f * t; x[c*4+0] = (av.x > 0) ? t : NEGBIG;
      t = w1 + pv.y; t = t >= 0.f ? t : 0.2f * t; x[c*4+1] = (av.y > 0) ? t : NEGBIG;
      t = w1 + pv.z; t = t >= 0.f ? t : 0.2f * t; x[c*4+2] = (av.z > 0) ? t : NEGBIG;
      t = w1 + pv.w; t = t >= 0.f ? t : 0.2f * t; x[c*4+3] = (av.w > 0) ? t : NEGBIG;
    }

    float m = x[0];
#pragma unroll
    for (int k = 1; k < 32; ++k) m = fmaxf(m, x[k]);
#pragma unroll
    for (int off = 32; off >= 1; off >>= 1) m = fmaxf(m, __shfl_xor(m, off));
    float sum = 0.f;
#pragma unroll
    for (int k = 0; k < 32; ++k) { x[k] = __expf(x[k] - m); sum += x[k]; }
#pragma unroll
    for (int off = 32; off >= 1; off >>= 1) sum += __shfl_xor(sum, off);
    float iv = 1.0f / sum;

    int row_local = wave * 2 + rr;
    int swz = row_local * 8;
    float* orow = att + (size_t)(rowbase + rr) * NN;
    unsigned short* srow = satt + row_local * 2048;
#pragma unroll
    for (int c = 0; c < 8; ++c) {
      int j = c * 256 + lane * 4;
      float a0 = x[c*4+0] * iv, a1 = x[c*4+1] * iv;
      float a2 = x[c*4+2] * iv, a3 = x[c*4+3] * iv;
      f32x4 ov = (f32x4){a0, a1, a2, a3};
      __builtin_nontemporal_store(ov, (f32x4*)(orow + j));
      // LDS: 4 bf16 (8B) at swizzled offset; groups of 8 permuted by swz
      int e = ((j & ~7) ^ swz) + (j & 7);
      union { short4 v4; unsigned short us[4]; } pk;
      pk.us[0] = f2bf_fast(a0); pk.us[1] = f2bf_fast(a1);
      pk.us[2] = f2bf_fast(a2); pk.us[3] = f2bf_fast(a3);
      *(short4*)(srow + e) = pk.v4;
    }
  }

  __syncthreads();

  // ---------------- phase 2: h_prime = att @ Wh, out = h + elu -------------
  int fW = wave * 32;
  int l15 = lane & 15, gq = lane >> 4, q8 = gq * 8;
  const unsigned short* WTb = WhT + (size_t)b * NF * NN;
  const unsigned short* aRow = satt + l15 * 2048;
  int swzA = l15 * 8;
  // frag-order B base: rows fW+nt*16+l15, k-octet gq, tile kk>>5
  const unsigned short* bbase = WTb + (fW + l15) * 32 + gq * 8;

  f32x4 acc[2];
#pragma unroll
  for (int nt = 0; nt < 2; ++nt) acc[nt] = (f32x4){0.f, 0.f, 0.f, 0.f};

  for (int kk = 0; kk < NN; kk += 32) {
    bf16x8 afr = *(const bf16x8*)(aRow + (((kk + q8) ^ swzA)));
    const unsigned short* bk = bbase + (kk >> 5) * 8192;
    bf16x8 bfr0 = *(const bf16x8*)(bk);
    bf16x8 bfr1 = *(const bf16x8*)(bk + 512);
    acc[0] = __builtin_amdgcn_mfma_f32_16x16x32_bf16(afr, bfr0, acc[0], 0, 0, 0);
    acc[1] = __builtin_amdgcn_mfma_f32_16x16x32_bf16(afr, bfr1, acc[1], 0, 0, 0);
  }

  int q4 = gq * 4;
#pragma unroll
  for (int nt = 0; nt < 2; ++nt)
#pragma unroll
    for (int r = 0; r < 4; ++r) {
      int i = i0 + q4 + r;
      int f = fW + nt * 16 + l15;
      size_t idx = ((size_t)(b * NN + i)) * NF + f;
      float hp = acc[nt][r];
      float el = hp > 0.f ? hp : expm1f(hp);
      float hv = __builtin_nontemporal_load(h + idx);
      __builtin_nontemporal_store(hv + el, out + idx);
    }
}

// ---------------------------------------------------------------------------
extern "C" void kernel_launch(void* const* d_in, const int* in_sizes, int n_in,
                              void* d_out, int out_size, void* d_ws, size_t ws_size,
                              hipStream_t stream) {
  // identify inputs by element count (all four are distinct)
  const float* h = nullptr; const int* adj = nullptr;
  const float* W = nullptr; const float* a = nullptr;
  for (int i = 0; i < n_in; ++i) {
    int s = in_sizes[i];
    if (s == NB * NN * NF) h = (const float*)d_in[i];
    else if (s == NB * NN * NN) adj = (const int*)d_in[i];
    else if (s == NF * NF) W = (const float*)d_in[i];
    else if (s == 2 * NF) a = (const float*)d_in[i];
  }

  float* out = (float*)d_out;                              // [8,2048,256] fp32
  float* att = out + (size_t)NB * NN * NF;                 // [8,2048,2048] fp32

  // ws footprint ~8.26 MB (proven safe; layouts reordered, sizes unchanged)
  char* ws = (char*)d_ws;
  unsigned short* WhT = (unsigned short*)ws;               // 8 MB frag-order [8][64][256][4][8]
  unsigned short* WTr = (unsigned short*)(ws + 8388608);   // 128 KB frag-order [8][256][4][8]
  float* u   = (float*)(ws + 8388608 + 131072);            // 1 KB
  float* v   = u + 256;                                    // 1 KB
  float* Wh1 = v + 256;                                    // 64 KB
  float* Wh2 = Wh1 + NB * NN;                              // 64 KB

  k_prep<<<257, 256, 0, stream>>>(W, a, WTr, u, v);
  k_mid<<<1024, 256, 0, stream>>>(h, WTr, u, v, WhT, Wh1, Wh2);
  k_fuse<<<NB * 128, 512, 0, stream>>>(adj, Wh1, Wh2, WhT, h, att, out);
}

// Round 11
// 342.937 us; speedup vs baseline: 1.3841x; 1.0126x over previous
//
#include <hip/hip_runtime.h>

#define NB 8
#define NN 2048
#define NF 256

typedef __attribute__((ext_vector_type(8))) short bf16x8;
typedef __attribute__((ext_vector_type(4))) float f32x4;
typedef __attribute__((ext_vector_type(4))) int i32x4;

// Fragment-ordered panel layout ("frag order"):
//   blob[kb][f][g][j]  (shorts)  kb=k/32, g=lane>>4 (k-octet), j=k&7
//   addr_sh = kb*8192 + f*32 + g*8 + j
// A wave's MFMA B-fragment load (rows f..f+15, k-octet per lane-quad) is then
// ONE contiguous 1KB load. The old [f][k] layout made every fragment load a
// 16-segment gather (~16x VMEM transaction slots) — proven R9: 176->124 us.

__device__ __forceinline__ unsigned short f2bf(float x) {
  union { float f; unsigned int i; } c; c.f = x;
  unsigned int r = c.i + 0x7FFFu + ((c.i >> 16) & 1u);
  return (unsigned short)(r >> 16);
}
// round-half-up bf16 (1 add + 1 shift) — hot convert paths
__device__ __forceinline__ unsigned short f2bf_fast(float x) {
  union { float f; unsigned int i; } c; c.f = x;
  return (unsigned short)((c.i + 0x8000u) >> 16);
}
__device__ __forceinline__ bf16x8 cvt8(float4 c0, float4 c1) {
  union { bf16x8 v8; unsigned short us[8]; } cu;
  cu.us[0] = f2bf_fast(c0.x); cu.us[1] = f2bf_fast(c0.y);
  cu.us[2] = f2bf_fast(c0.z); cu.us[3] = f2bf_fast(c0.w);
  cu.us[4] = f2bf_fast(c1.x); cu.us[5] = f2bf_fast(c1.y);
  cu.us[6] = f2bf_fast(c1.z); cu.us[7] = f2bf_fast(c1.w);
  return cu.v8;
}

// ---------------------------------------------------------------------------
// k_prep: WTr_frag[k/32][f][g][j] = bf16(W[k][f]);  u = W@a1, v = W@a2 (fp32)
// ---------------------------------------------------------------------------
__global__ __launch_bounds__(256) void k_prep(
    const float* __restrict__ W, const float* __restrict__ a,
    unsigned short* __restrict__ WT, float* __restrict__ u, float* __restrict__ v) {
  int t = threadIdx.x;
  if (blockIdx.x < 256) {
    int k = blockIdx.x;
    // frag-order: kb=k>>5, f=t, g=(k>>3)&3, j=k&7
    WT[(k >> 5) * 8192 + t * 32 + ((k >> 3) & 3) * 8 + (k & 7)] = f2bf(W[k * 256 + t]);
  } else {
    float su = 0.f, sv = 0.f;
    for (int o = 0; o < 256; ++o) {
      float w = W[t * 256 + o];
      su += w * a[o];
      sv += w * a[256 + o];
    }
    u[t] = su; v[t] = sv;
  }
}

// ---------------------------------------------------------------------------
// k_mid: WhT_frag = W^T h^T (frag-order) AND Wh1/Wh2 = h.u / h.v, one h pass.
// R11: the h-read was the LAST 16-segment gather (lanes 0..15 of a B-fragment
// load hit 16 rows 1KB apart) — same pathology R9 fixed for WhT (176->124us).
// Now: stage the 16x256 fp32 tile through 8KB XOR-swizzled bf16 LDS.
//   - wave w loads rows w*4..w*4+3, each row = 64 lanes x float4 = 1KB,
//     fully coalesced (1 segment/instruction);
//   - u/v dot partials computed fp32 during staging, 64-lane butterfly,
//     distributed over all 4 waves (was: wave 0 only);
//   - MFMA B-fragments read from LDS (swizzle byte ^= (row&7)<<4 -> <=4-way).
// WTr frag-order reads and WhT frag-order writes unchanged from R9 (proven).
// grid 1024: b(8) x itile(128,16 rows); 256 thr / 4 waves; LDS 8 KB.
// ---------------------------------------------------------------------------
__global__ __launch_bounds__(256) void k_mid(
    const float* __restrict__ h, const unsigned short* __restrict__ WTr,
    const float* __restrict__ u, const float* __restrict__ v,
    unsigned short* __restrict__ WhT, float* __restrict__ Wh1, float* __restrict__ Wh2) {
  __shared__ __align__(16) unsigned short sh[16 * 256];  // 8 KB bf16, swizzled
  int bx = blockIdx.x;
  int b = bx >> 7;
  int iW = (bx & 127) * 16;
  int wave = threadIdx.x >> 6, lane = threadIdx.x & 63;
  const float* hB = h + (size_t)b * NN * NF;

  // ---- stage 16 rows coalesced + fp32 u/v partials ----
  float pu[4], pw[4];
  {
    int c4 = lane * 4;                      // this lane's 4 columns
    const float* uc = u + c4;
    const float* vc = v + c4;
#pragma unroll
    for (int it = 0; it < 4; ++it) {
      int r = wave * 4 + it;                // local row 0..15
      const float* p = hB + (size_t)(iW + r) * NF + c4;
      float4 hv = *(const float4*)p;
      pu[it] = hv.x*uc[0] + hv.y*uc[1] + hv.z*uc[2] + hv.w*uc[3];
      pw[it] = hv.x*vc[0] + hv.y*vc[1] + hv.z*vc[2] + hv.w*vc[3];
      int byte = r * 512 + ((c4 * 2) ^ ((r & 7) << 4));
      union { short4 v4; unsigned short us[4]; } pk;
      pk.us[0] = f2bf_fast(hv.x); pk.us[1] = f2bf_fast(hv.y);
      pk.us[2] = f2bf_fast(hv.z); pk.us[3] = f2bf_fast(hv.w);
      *(short4*)((char*)sh + byte) = pk.v4;
    }
  }
#pragma unroll
  for (int it = 0; it < 4; ++it)
#pragma unroll
    for (int off = 32; off >= 1; off >>= 1) {
      pu[it] += __shfl_xor(pu[it], off);
      pw[it] += __shfl_xor(pw[it], off);
    }
  if (lane == 0) {
#pragma unroll
    for (int it = 0; it < 4; ++it) {
      int row = b * NN + iW + wave * 4 + it;
      Wh1[row] = pu[it];
      Wh2[row] = pw[it];
    }
  }
  __syncthreads();

  // ---- MFMA: A = WTr frag-order (global, coalesced), B = h tile from LDS ----
  int fW = wave * 64;
  int l15 = lane & 15, gq = lane >> 4, q8 = gq * 8;
  const unsigned short* wf = WTr + (fW + l15) * 32 + gq * 8;

  f32x4 acc[4];
#pragma unroll
  for (int ft = 0; ft < 4; ++ft) acc[ft] = (f32x4){0.f, 0.f, 0.f, 0.f};

  for (int k0 = 0; k0 < NF; k0 += 32) {
    int byte = l15 * 512 + ((((k0 + q8) * 2)) ^ ((l15 & 7) << 4));
    bf16x8 bfr = *(const bf16x8*)((const char*)sh + byte);
    const unsigned short* wk = wf + (k0 >> 5) * 8192;
#pragma unroll
    for (int ft = 0; ft < 4; ++ft) {
      bf16x8 af = *(const bf16x8*)(wk + ft * 512);   // 16 rows x 32 sh
      acc[ft] = __builtin_amdgcn_mfma_f32_16x16x32_bf16(af, bfr, acc[ft], 0, 0, 0);
    }
  }

  // frag-order WhT write: k-dim of phase2 is i here (unchanged from R9).
  unsigned short* WhTb = WhT + (size_t)b * NF * NN;
  int kb = iW >> 5;
  int gg = ((iW & 16) + l15) >> 3;
  int jj = l15 & 7;
  int q4 = gq * 4;
#pragma unroll
  for (int ft = 0; ft < 4; ++ft)
#pragma unroll
    for (int r = 0; r < 4; ++r) {
      int f = fW + ft * 16 + q4 + r;
      WhTb[kb * 8192 + f * 32 + gg * 8 + jj] = f2bf(acc[ft][r]);
    }
}

// ---------------------------------------------------------------------------
// k_fuse: softmax (16 rows) + att@WhT + h+elu epilogue, one block per row-tile.
// EXACT R9 text (proven: 124 us, absmax 0.031). R10's phase-1 ILP rewrite
// failed correctness (absmax 0.36) for a cause not identifiable by review —
// reverted per rigor discipline.
// Keeps: frag-order B (R9), XCD-affine swizzle, nt on zero-reuse streams.
// grid 1024: b(8) x itile(128,16i); 512 thr / 8 waves; LDS 64 KB.
// ---------------------------------------------------------------------------
__global__ __launch_bounds__(512, 4) void k_fuse(
    const int* __restrict__ adj, const float* __restrict__ Wh1,
    const float* __restrict__ Wh2, const unsigned short* __restrict__ WhT,
    const float* __restrict__ h, float* __restrict__ att, float* __restrict__ out) {
  __shared__ unsigned short satt[16 * 2048];  // 64 KB, XOR-swizzled rows
  const float NEGBIG = -9.0e15f;
  int bx = blockIdx.x;
  bx = (bx & 7) * 128 + (bx >> 3);   // XCD-affine remap (bijective on [0,1024))
  int b = bx >> 7;
  int i0 = (bx & 127) * 16;
  int wave = threadIdx.x >> 6, lane = threadIdx.x & 63;
  const float* w2 = Wh2 + ((size_t)b << 11);

  // ---------------- phase 1: masked-softmax, one row at a time -------------
  int rowbase = b * NN + i0 + wave * 2;
#pragma unroll
  for (int rr = 0; rr < 2; ++rr) {
    const int* arow = adj + (size_t)(rowbase + rr) * NN;
    float w1 = Wh1[rowbase + rr];
    float x[32];
#pragma unroll
    for (int c = 0; c < 8; ++c) {
      int j = c * 256 + lane * 4;
      i32x4 av = __builtin_nontemporal_load((const i32x4*)(arow + j));
      float4 pv = *(const float4*)(w2 + j);
      float t;
      t = w1 + pv.x; t = t >= 0.f ? t : 0.2f * t; x[c*4+0] = (av.x > 0) ? t : NEGBIG;
      t = w1 + pv.y; t = t >= 0.f ? t : 0.2f * t; x[c*4+1] = (av.y > 0) ? t : NEGBIG;
      t = w1 + pv.z; t = t >= 0.f ? t : 0.2f * t; x[c*4+2] = (av.z > 0) ? t : NEGBIG;
      t = w1 + pv.w; t = t >= 0.f ? t : 0.2f * t; x[c*4+3] = (av.w > 0) ? t : NEGBIG;
    }

    float m = x[0];
#pragma unroll
    for (int k = 1; k < 32; ++k) m = fmaxf(m, x[k]);
#pragma unroll
    for (int off = 32; off >= 1; off >>= 1) m = fmaxf(m, __shfl_xor(m, off));
    float sum = 0.f;
#pragma unroll
    for (int k = 0; k < 32; ++k) { x[k] = __expf(x[k] - m); sum += x[k]; }
#pragma unroll
    for (int off = 32; off >= 1; off >>= 1) sum += __shfl_xor(sum, off);
    float iv = 1.0f / sum;

    int row_local = wave * 2 + rr;
    int swz = row_local * 8;
    float* orow = att + (size_t)(rowbase + rr) * NN;
    unsigned short* srow = satt + row_local * 2048;
#pragma unroll
    for (int c = 0; c < 8; ++c) {
      int j = c * 256 + lane * 4;
      float a0 = x[c*4+0] * iv, a1 = x[c*4+1] * iv;
      float a2 = x[c*4+2] * iv, a3 = x[c*4+3] * iv;
      f32x4 ov = (f32x4){a0, a1, a2, a3};
      __builtin_nontemporal_store(ov, (f32x4*)(orow + j));
      // LDS: 4 bf16 (8B) at swizzled offset; groups of 8 permuted by swz
      int e = ((j & ~7) ^ swz) + (j & 7);
      union { short4 v4; unsigned short us[4]; } pk;
      pk.us[0] = f2bf_fast(a0); pk.us[1] = f2bf_fast(a1);
      pk.us[2] = f2bf_fast(a2); pk.us[3] = f2bf_fast(a3);
      *(short4*)(srow + e) = pk.v4;
    }
  }

  __syncthreads();

  // ---------------- phase 2: h_prime = att @ Wh, out = h + elu -------------
  int fW = wave * 32;
  int l15 = lane & 15, gq = lane >> 4, q8 = gq * 8;
  const unsigned short* WTb = WhT + (size_t)b * NF * NN;
  const unsigned short* aRow = satt + l15 * 2048;
  int swzA = l15 * 8;
  // frag-order B base: rows fW+nt*16+l15, k-octet gq, tile kk>>5
  const unsigned short* bbase = WTb + (fW + l15) * 32 + gq * 8;

  f32x4 acc[2];
#pragma unroll
  for (int nt = 0; nt < 2; ++nt) acc[nt] = (f32x4){0.f, 0.f, 0.f, 0.f};

  for (int kk = 0; kk < NN; kk += 32) {
    bf16x8 afr = *(const bf16x8*)(aRow + (((kk + q8) ^ swzA)));
    const unsigned short* bk = bbase + (kk >> 5) * 8192;
    bf16x8 bfr0 = *(const bf16x8*)(bk);
    bf16x8 bfr1 = *(const bf16x8*)(bk + 512);
    acc[0] = __builtin_amdgcn_mfma_f32_16x16x32_bf16(afr, bfr0, acc[0], 0, 0, 0);
    acc[1] = __builtin_amdgcn_mfma_f32_16x16x32_bf16(afr, bfr1, acc[1], 0, 0, 0);
  }

  int q4 = gq * 4;
#pragma unroll
  for (int nt = 0; nt < 2; ++nt)
#pragma unroll
    for (int r = 0; r < 4; ++r) {
      int i = i0 + q4 + r;
      int f = fW + nt * 16 + l15;
      size_t idx = ((size_t)(b * NN + i)) * NF + f;
      float hp = acc[nt][r];
      float el = hp > 0.f ? hp : expm1f(hp);
      float hv = __builtin_nontemporal_load(h + idx);
      __builtin_nontemporal_store(hv + el, out + idx);
    }
}

// ---------------------------------------------------------------------------
extern "C" void kernel_launch(void* const* d_in, const int* in_sizes, int n_in,
                              void* d_out, int out_size, void* d_ws, size_t ws_size,
                              hipStream_t stream) {
  // identify inputs by element count (all four are distinct)
  const float* h = nullptr; const int* adj = nullptr;
  const float* W = nullptr; const float* a = nullptr;
  for (int i = 0; i < n_in; ++i) {
    int s = in_sizes[i];
    if (s == NB * NN * NF) h = (const float*)d_in[i];
    else if (s == NB * NN * NN) adj = (const int*)d_in[i];
    else if (s == NF * NF) W = (const float*)d_in[i];
    else if (s == 2 * NF) a = (const float*)d_in[i];
  }

  float* out = (float*)d_out;                              // [8,2048,256] fp32
  float* att = out + (size_t)NB * NN * NF;                 // [8,2048,2048] fp32

  // ws footprint ~8.26 MB (proven safe; layouts reordered, sizes unchanged)
  char* ws = (char*)d_ws;
  unsigned short* WhT = (unsigned short*)ws;               // 8 MB frag-order [8][64][256][4][8]
  unsigned short* WTr = (unsigned short*)(ws + 8388608);   // 128 KB frag-order [8][256][4][8]
  float* u   = (float*)(ws + 8388608 + 131072);            // 1 KB
  float* v   = u + 256;                                    // 1 KB
  float* Wh1 = v + 256;                                    // 64 KB
  float* Wh2 = Wh1 + NB * NN;                              // 64 KB

  k_prep<<<257, 256, 0, stream>>>(W, a, WTr, u, v);
  k_mid<<<1024, 256, 0, stream>>>(h, WTr, u, v, WhT, Wh1, Wh2);
  k_fuse<<<NB * 128, 512, 0, stream>>>(adj, Wh1, Wh2, WhT, h, att, out);
}